// Round 3
// baseline (459.090 us; speedup 1.0000x reference)
//
#include <hip/hip_runtime.h>
#include <hip/hip_bf16.h>

typedef __attribute__((ext_vector_type(8))) short short8;
typedef __attribute__((ext_vector_type(4))) float f32x4;

struct XPtrs { const float* p[17]; };
struct Bases { int v[18]; };

#define CPB 10  // chunks (of 128 rows) per block

__device__ __forceinline__ unsigned short f2bf(float f) {
  unsigned u = __float_as_uint(f);
  return (unsigned short)((u + 0x7fffu + ((u >> 16) & 1u)) >> 16);  // RNE
}

// ---------------- pre-kernel: W fp32 -> bf16, fragment-packed into ws ----
// Per diag d: 2048 slots of 16 B. slot = sg*128 + n  (sg = s*4 + g)
// slot holds W[d][n][k] for k = sg*8 .. sg*8+7 as 8 bf16.
__global__ __launch_bounds__(1024) void convert_w_kernel(
    const float* __restrict__ W, unsigned short* __restrict__ ws) {
  const int tid = blockIdx.x * 1024 + threadIdx.x;  // 0 .. 17*2048-1
  const int d  = tid >> 11;
  const int s2 = tid & 2047;
  const int sg = s2 >> 7;     // 0..15
  const int n  = s2 & 127;
  const float* src = W + ((size_t)d * 128 + n) * 128 + sg * 8;
  float4 a = *(const float4*)(src);
  float4 b = *(const float4*)(src + 4);
  unsigned u0 = (unsigned)f2bf(a.x) | ((unsigned)f2bf(a.y) << 16);
  unsigned u1 = (unsigned)f2bf(a.z) | ((unsigned)f2bf(a.w) << 16);
  unsigned u2 = (unsigned)f2bf(b.x) | ((unsigned)f2bf(b.y) << 16);
  unsigned u3 = (unsigned)f2bf(b.z) | ((unsigned)f2bf(b.w) << 16);
  *(uint4*)(ws + (size_t)tid * 8) = make_uint4(u0, u1, u2, u3);
}

// ---------------- main kernel ----------------
// 512 threads = 8 waves. Block handles up to CPB chunks of 128 rows, all in
// one diagonal. W+bias staged to LDS once; steady-state loop is barrier-free
// with register prefetch of the next chunk's X.
__global__ __launch_bounds__(512, 4) void diag_linear_kernel(
    XPtrs xp, Bases bb, const unsigned short* __restrict__ wsrc,
    const float* __restrict__ bias, float* __restrict__ out) {
  const int bid = blockIdx.x;
  int d = 0;
#pragma unroll
  for (int i = 1; i < 17; ++i) d += (bid >= bb.v[i]) ? 1 : 0;
  const int L = 9 - ((d < 8) ? (8 - d) : (d - 8));
  const int start = (d > 8) ? (d - 8) : 0;
  const float* __restrict__ x = xp.p[d];
  const int nchunks = 64 * L;
  const int ck0 = (bid - bb.v[d]) * CPB;
  const int nit = min(CPB, nchunks - ck0);

  const int t = threadIdx.x;
  const int lane = t & 63;
  const int wave = t >> 6;       // 0..7
  const int lr = lane & 15;
  const int lg = lane >> 4;

  __shared__ unsigned short wlds[2048 * 8];  // 32 KiB
  __shared__ float blds[128];                // bias

  // ---- stage W[d] (pre-packed bf16) via async global->LDS, 16B/lane ----
  {
    const unsigned short* gw = wsrc + (size_t)d * 16384;
    typedef const __attribute__((address_space(1))) unsigned int* gas_u32;
    typedef __attribute__((address_space(3))) unsigned int* las_u32;
#pragma unroll
    for (int r = 0; r < 4; ++r) {
      const int slotbase = (wave * 4 + r) * 64;
      __builtin_amdgcn_global_load_lds(
          (gas_u32)(const void*)(gw + (size_t)(slotbase + lane) * 8),
          (las_u32)(void*)(wlds + (size_t)slotbase * 8),
          16, 0, 0);
    }
    if (wave < 2) {
      typedef const __attribute__((address_space(1))) unsigned int* g32;
      typedef __attribute__((address_space(3))) unsigned int* l32;
      __builtin_amdgcn_global_load_lds(
          (g32)(const void*)(bias + d * 128 + wave * 64 + lane),
          (l32)(void*)(blds + wave * 64), 4, 0, 0);
    }
  }

  // ---- prefetch chunk ck0 into registers ----
  float4 pf[8];
  {
    const float* xr = x + ((size_t)(ck0 * 128 + wave * 16 + lr)) * 128 + lg * 8;
#pragma unroll
    for (int s = 0; s < 4; ++s) {
      pf[2 * s]     = *(const float4*)(xr + s * 32);
      pf[2 * s + 1] = *(const float4*)(xr + s * 32 + 4);
    }
  }

  __syncthreads();   // W + bias resident (sync drains vmcnt)

  for (int it = 0; it < nit; ++it) {
    const int ck = ck0 + it;

    // convert current prefetch -> bf16 fragments
    short8 xf[4];
#pragma unroll
    for (int s = 0; s < 4; ++s) {
      float4 a0 = pf[2 * s], a1 = pf[2 * s + 1];
      short8 f;
      f[0] = (short)f2bf(a0.x); f[1] = (short)f2bf(a0.y);
      f[2] = (short)f2bf(a0.z); f[3] = (short)f2bf(a0.w);
      f[4] = (short)f2bf(a1.x); f[5] = (short)f2bf(a1.y);
      f[6] = (short)f2bf(a1.z); f[7] = (short)f2bf(a1.w);
      xf[s] = f;
    }

    // issue next chunk's loads early (overlap MFMA + stores)
    if (it + 1 < nit) {
      const float* xr =
          x + ((size_t)((ck + 1) * 128 + wave * 16 + lr)) * 128 + lg * 8;
#pragma unroll
      for (int s = 0; s < 4; ++s) {
        pf[2 * s]     = *(const float4*)(xr + s * 32);
        pf[2 * s + 1] = *(const float4*)(xr + s * 32 + 4);
      }
    }

    // MFMA: A = W frag (couts), B = X frag (16 batch rows)
    f32x4 acc[8];
#pragma unroll
    for (int nb = 0; nb < 8; ++nb) acc[nb] = (f32x4){0.f, 0.f, 0.f, 0.f};
#pragma unroll
    for (int s = 0; s < 4; ++s) {
#pragma unroll
      for (int nb = 0; nb < 8; ++nb) {
        short8 wf = *(const short8*)
            &wlds[(size_t)((s * 4 + lg) * 128 + nb * 16 + lr) * 8];
        acc[nb] = __builtin_amdgcn_mfma_f32_16x16x32_bf16(wf, xf[s], acc[nb], 0, 0, 0);
      }
    }

    // epilogue: D[cout = nb*16+lg*4+v][brow = lr]; bias from LDS (lgkm path)
    const int f = ck * 128 + wave * 16 + lr;
    const unsigned b = (unsigned)f / (unsigned)L;
    const int l = f - (int)b * L;
    float* orow = out + (size_t)b * 10368 + (size_t)(start * 8 + d) * 128
                  + (size_t)l * 1024 + lg * 4;
#pragma unroll
    for (int nb = 0; nb < 8; ++nb) {
      f32x4 bv = *(const f32x4*)&blds[nb * 16 + lg * 4];
      *(f32x4*)(orow + nb * 16) = acc[nb] + bv;
    }
  }
}

extern "C" void kernel_launch(void* const* d_in, const int* in_sizes, int n_in,
                              void* d_out, int out_size, void* d_ws, size_t ws_size,
                              hipStream_t stream) {
  const float* W = (const float*)d_in[0];
  const float* bias = (const float*)d_in[1];
  XPtrs xp;
  for (int i = 0; i < 17; ++i) xp.p[i] = (const float*)d_in[2 + i];
  float* out = (float*)d_out;
  unsigned short* ws = (unsigned short*)d_ws;   // 17*2048*16 B = 544 KiB

  Bases bb;
  int base = 0;
  for (int i = 0; i < 17; ++i) {
    bb.v[i] = base;
    int L = 9 - ((i < 8) ? (8 - i) : (i - 8));
    base += (64 * L + CPB - 1) / CPB;
  }
  bb.v[17] = base;   // 526 blocks

  convert_w_kernel<<<34, 1024, 0, stream>>>(W, ws);
  diag_linear_kernel<<<base, 512, 0, stream>>>(xp, bb, ws, bias, out);
}

// Round 4
// 402.799 us; speedup vs baseline: 1.1397x; 1.1397x over previous
//
#include <hip/hip_runtime.h>
#include <hip/hip_bf16.h>

typedef __attribute__((ext_vector_type(8))) short short8;
typedef __attribute__((ext_vector_type(4))) float f32x4;

struct XPtrs { const float* p[17]; };
struct Bases { int v[18]; };

#define CPB 10  // units (of 64 rows) per block

__device__ __forceinline__ unsigned short f2bf(float f) {
  unsigned u = __float_as_uint(f);
  return (unsigned short)((u + 0x7fffu + ((u >> 16) & 1u)) >> 16);  // RNE
}

// ---------------- pre-kernel: W fp32 -> bf16, fragment-packed into ws ----
// Per diag d: 2048 slots of 16 B. slot = sg*128 + n  (sg = s*4 + g)
// slot holds W[d][n][k] for k = sg*8 .. sg*8+7 as 8 bf16.
__global__ __launch_bounds__(1024) void convert_w_kernel(
    const float* __restrict__ W, unsigned short* __restrict__ ws) {
  const int tid = blockIdx.x * 1024 + threadIdx.x;  // 0 .. 17*2048-1
  const int d  = tid >> 11;
  const int s2 = tid & 2047;
  const int sg = s2 >> 7;     // 0..15
  const int n  = s2 & 127;
  const float* src = W + ((size_t)d * 128 + n) * 128 + sg * 8;
  float4 a = *(const float4*)(src);
  float4 b = *(const float4*)(src + 4);
  unsigned u0 = (unsigned)f2bf(a.x) | ((unsigned)f2bf(a.y) << 16);
  unsigned u1 = (unsigned)f2bf(a.z) | ((unsigned)f2bf(a.w) << 16);
  unsigned u2 = (unsigned)f2bf(b.x) | ((unsigned)f2bf(b.y) << 16);
  unsigned u3 = (unsigned)f2bf(b.z) | ((unsigned)f2bf(b.w) << 16);
  *(uint4*)(ws + (size_t)tid * 8) = make_uint4(u0, u1, u2, u3);
}

// ---------------- main kernel ----------------
// 256 threads = 4 waves. Block owns up to CPB units of 64 rows in ONE
// diagonal. W+bias staged to LDS once (no further barriers). Steady-state:
// convert current unit -> issue next unit's loads -> MFMA -> store.
__global__ __launch_bounds__(256, 4) void diag_linear_kernel(
    XPtrs xp, Bases bb, const unsigned short* __restrict__ wsrc,
    const float* __restrict__ bias, float* __restrict__ out) {
  const int bid = blockIdx.x;
  int d = 0;
#pragma unroll
  for (int i = 1; i < 17; ++i) d += (bid >= bb.v[i]) ? 1 : 0;
  const int L = 9 - ((d < 8) ? (8 - d) : (d - 8));
  const int start = (d > 8) ? (d - 8) : 0;
  const float* __restrict__ x = xp.p[d];
  const int nunits = 128 * L;                // units of 64 rows in this diag
  const int u0 = (bid - bb.v[d]) * CPB;
  const int nit = min(CPB, nunits - u0);

  const int t = threadIdx.x;
  const int lane = t & 63;
  const int wave = t >> 6;       // 0..3
  const int lr = lane & 15;
  const int lg = lane >> 4;

  __shared__ unsigned short wlds[2048 * 8];  // 32 KiB
  __shared__ float blds[128];                // bias

  // ---- stage W[d] (pre-packed bf16) + bias via async global->LDS ----
  {
    const unsigned short* gw = wsrc + (size_t)d * 16384;
    typedef const __attribute__((address_space(1))) unsigned int* gas_u32;
    typedef __attribute__((address_space(3))) unsigned int* las_u32;
#pragma unroll
    for (int r = 0; r < 8; ++r) {
      const int slotbase = (wave * 8 + r) * 64;
      __builtin_amdgcn_global_load_lds(
          (gas_u32)(const void*)(gw + (size_t)(slotbase + lane) * 8),
          (las_u32)(void*)(wlds + (size_t)slotbase * 8),
          16, 0, 0);
    }
    if (wave < 2) {
      __builtin_amdgcn_global_load_lds(
          (gas_u32)(const void*)(bias + d * 128 + wave * 64 + lane),
          (las_u32)(void*)(blds + wave * 64), 4, 0, 0);
    }
  }

  // ---- prefetch unit u0 into registers (overlaps W staging) ----
  float4 pf[8];
  {
    const float* xr = x + ((size_t)(u0 * 64 + wave * 16 + lr)) * 128 + lg * 8;
#pragma unroll
    for (int s = 0; s < 4; ++s) {
      pf[2 * s]     = *(const float4*)(xr + s * 32);
      pf[2 * s + 1] = *(const float4*)(xr + s * 32 + 4);
    }
  }

  __syncthreads();   // W + bias resident (sync drains vmcnt)

  for (int it = 0; it < nit; ++it) {
    const int u = u0 + it;

    // convert current prefetch -> bf16 fragments (pf dies here)
    short8 xf[4];
#pragma unroll
    for (int s = 0; s < 4; ++s) {
      float4 a0 = pf[2 * s], a1 = pf[2 * s + 1];
      short8 f;
      f[0] = (short)f2bf(a0.x); f[1] = (short)f2bf(a0.y);
      f[2] = (short)f2bf(a0.z); f[3] = (short)f2bf(a0.w);
      f[4] = (short)f2bf(a1.x); f[5] = (short)f2bf(a1.y);
      f[6] = (short)f2bf(a1.z); f[7] = (short)f2bf(a1.w);
      xf[s] = f;
    }

    // issue next unit's loads early (overlap MFMA + stores)
    if (it + 1 < nit) {
      const float* xr =
          x + ((size_t)((u + 1) * 64 + wave * 16 + lr)) * 128 + lg * 8;
#pragma unroll
      for (int s = 0; s < 4; ++s) {
        pf[2 * s]     = *(const float4*)(xr + s * 32);
        pf[2 * s + 1] = *(const float4*)(xr + s * 32 + 4);
      }
    }

    // acc init = bias (bias[cout] replicated across batch cols)
    f32x4 acc[8];
#pragma unroll
    for (int nb = 0; nb < 8; ++nb)
      acc[nb] = *(const f32x4*)&blds[nb * 16 + lg * 4];

    // MFMA: A = W frag (couts), B = X frag (16 batch rows)
#pragma unroll
    for (int s = 0; s < 4; ++s) {
#pragma unroll
      for (int nb = 0; nb < 8; ++nb) {
        short8 wf = *(const short8*)
            &wlds[(size_t)((s * 4 + lg) * 128 + nb * 16 + lr) * 8];
        acc[nb] = __builtin_amdgcn_mfma_f32_16x16x32_bf16(wf, xf[s], acc[nb], 0, 0, 0);
      }
    }

    // epilogue: D[cout = nb*16+lg*4+v][brow = lr]
    const int f = u * 64 + wave * 16 + lr;
    const unsigned b = (unsigned)f / (unsigned)L;
    const int l = f - (int)b * L;
    float* orow = out + (size_t)b * 10368 + (size_t)(start * 8 + d) * 128
                  + (size_t)l * 1024 + lg * 4;
#pragma unroll
    for (int nb = 0; nb < 8; ++nb)
      *(f32x4*)(orow + nb * 16) = acc[nb];
  }
}

extern "C" void kernel_launch(void* const* d_in, const int* in_sizes, int n_in,
                              void* d_out, int out_size, void* d_ws, size_t ws_size,
                              hipStream_t stream) {
  const float* W = (const float*)d_in[0];
  const float* bias = (const float*)d_in[1];
  XPtrs xp;
  for (int i = 0; i < 17; ++i) xp.p[i] = (const float*)d_in[2 + i];
  float* out = (float*)d_out;
  unsigned short* ws = (unsigned short*)d_ws;   // 17*2048*16 B = 544 KiB

  Bases bb;
  int base = 0;
  for (int i = 0; i < 17; ++i) {
    bb.v[i] = base;
    int L = 9 - ((i < 8) ? (8 - i) : (i - 8));
    base += (128 * L + CPB - 1) / CPB;
  }
  bb.v[17] = base;   // ~1038 blocks

  convert_w_kernel<<<34, 1024, 0, stream>>>(W, ws);
  diag_linear_kernel<<<base, 256, 0, stream>>>(xp, bb, ws, bias, out);
}

// Round 5
// 166.304 us; speedup vs baseline: 2.7605x; 2.4221x over previous
//
#include <hip/hip_runtime.h>
#include <hip/hip_bf16.h>

typedef __attribute__((ext_vector_type(8))) short short8;
typedef __attribute__((ext_vector_type(4))) float f32x4;

struct XPtrs { const float* p[17]; };
struct Bases { int v[18]; };

__device__ __forceinline__ unsigned short f2bf(float f) {
  unsigned u = __float_as_uint(f);
  return (unsigned short)((u + 0x7fffu + ((u >> 16) & 1u)) >> 16);  // RNE
}

// ---------------- pre-kernel: W fp32 -> bf16, fragment-packed into ws ----
// Per diag d: 2048 slots of 16 B. slot = sg*128 + n  (sg = s*4 + g)
// slot holds W[d][n][k] for k = sg*8 .. sg*8+7 as 8 bf16.
__global__ __launch_bounds__(1024) void convert_w_kernel(
    const float* __restrict__ W, unsigned short* __restrict__ ws) {
  const int tid = blockIdx.x * 1024 + threadIdx.x;  // 0 .. 17*2048-1
  const int d  = tid >> 11;
  const int s2 = tid & 2047;
  const int sg = s2 >> 7;     // 0..15
  const int n  = s2 & 127;
  const float* src = W + ((size_t)d * 128 + n) * 128 + sg * 8;
  float4 a = *(const float4*)(src);
  float4 b = *(const float4*)(src + 4);
  unsigned u0 = (unsigned)f2bf(a.x) | ((unsigned)f2bf(a.y) << 16);
  unsigned u1 = (unsigned)f2bf(a.z) | ((unsigned)f2bf(a.w) << 16);
  unsigned u2 = (unsigned)f2bf(b.x) | ((unsigned)f2bf(b.y) << 16);
  unsigned u3 = (unsigned)f2bf(b.z) | ((unsigned)f2bf(b.w) << 16);
  *(uint4*)(ws + (size_t)tid * 8) = make_uint4(u0, u1, u2, u3);
}

// ---------------- main kernel ----------------
// One block = 256 flat rows of ONE diagonal (2 sub-tiles of 128 rows).
// 4 waves; per sub-tile each wave owns 32 rows (2 x 16). MFMA operands
// swapped (A=W frag, B=X frag) so each lane's acc quad = 4 consecutive
// couts of one batch row -> plain dwordx4 stores, 512B contiguous per row
// (full-line L2 write-combining; no NT).
__global__ __launch_bounds__(256) void diag_linear_kernel(
    XPtrs xp, Bases bb, const unsigned short* __restrict__ wsrc,
    const float* __restrict__ bias, float* __restrict__ out) {
  const int bid = blockIdx.x;
  int d = 0;
#pragma unroll
  for (int i = 1; i < 17; ++i) d += (bid >= bb.v[i]) ? 1 : 0;
  const int L = 9 - ((d < 8) ? (8 - d) : (d - 8));
  const int start = (d > 8) ? (d - 8) : 0;
  const float* __restrict__ x = xp.p[d];
  const int chunk = bid - bb.v[d];
  const int m0 = chunk * 256;

  const int t = threadIdx.x;
  const int lane = t & 63;
  const int wave = t >> 6;
  const int lr = lane & 15;
  const int lg = lane >> 4;

  __shared__ unsigned short wlds[2048 * 8];  // 32 KiB
  __shared__ float blds[128];                // bias

  // ---- stage W[d] (pre-packed bf16) + bias via async global->LDS ----
  {
    const unsigned short* gw = wsrc + (size_t)d * 16384;
    typedef const __attribute__((address_space(1))) unsigned int* gas_u32;
    typedef __attribute__((address_space(3))) unsigned int* las_u32;
#pragma unroll
    for (int r = 0; r < 8; ++r) {
      const int slotbase = (wave * 8 + r) * 64;
      __builtin_amdgcn_global_load_lds(
          (gas_u32)(const void*)(gw + (size_t)(slotbase + lane) * 8),
          (las_u32)(void*)(wlds + (size_t)slotbase * 8),
          16, 0, 0);
    }
    if (t < 32) {  // one wave: lanes 0..31 -> blds[0..127], 16B/lane
      __builtin_amdgcn_global_load_lds(
          (gas_u32)(const void*)(bias + d * 128 + t * 4),
          (las_u32)(void*)(blds), 16, 0, 0);
    }
  }

  __syncthreads();   // W + bias resident (sync drains vmcnt)

#pragma unroll
  for (int sub = 0; sub < 2; ++sub) {
    const int m0s = m0 + sub * 128 + wave * 32;

    // ---- load X fragments (B operand): rows m0s+mb*16+lr, k=s*32+lg*8 ----
    short8 xf[2][4];
#pragma unroll
    for (int mb = 0; mb < 2; ++mb) {
      const float* xr = x + (size_t)(m0s + mb * 16 + lr) * 128;
#pragma unroll
      for (int s = 0; s < 4; ++s) {
        float4 a0 = *(const float4*)(xr + s * 32 + lg * 8);
        float4 a1 = *(const float4*)(xr + s * 32 + lg * 8 + 4);
        short8 f;
        f[0] = (short)f2bf(a0.x); f[1] = (short)f2bf(a0.y);
        f[2] = (short)f2bf(a0.z); f[3] = (short)f2bf(a0.w);
        f[4] = (short)f2bf(a1.x); f[5] = (short)f2bf(a1.y);
        f[6] = (short)f2bf(a1.z); f[7] = (short)f2bf(a1.w);
        xf[mb][s] = f;
      }
    }

    // ---- acc init = bias (from LDS; lane quad = couts nb*16+lg*4+0..3) ----
    f32x4 acc[8][2];
#pragma unroll
    for (int nb = 0; nb < 8; ++nb) {
      f32x4 bv = *(const f32x4*)&blds[nb * 16 + lg * 4];
      acc[nb][0] = bv;
      acc[nb][1] = bv;
    }

    // ---- MFMA: A = W frag (couts), B = X frag (batch rows) ----
#pragma unroll
    for (int s = 0; s < 4; ++s) {
#pragma unroll
      for (int nb = 0; nb < 8; ++nb) {
        short8 wf = *(const short8*)
            &wlds[(size_t)((s * 4 + lg) * 128 + nb * 16 + lr) * 8];
        acc[nb][0] = __builtin_amdgcn_mfma_f32_16x16x32_bf16(wf, xf[0][s], acc[nb][0], 0, 0, 0);
        acc[nb][1] = __builtin_amdgcn_mfma_f32_16x16x32_bf16(wf, xf[1][s], acc[nb][1], 0, 0, 0);
      }
    }

    // ---- epilogue: D[cout = nb*16+lg*4+v][brow = mb*16+lr] ----
#pragma unroll
    for (int mb = 0; mb < 2; ++mb) {
      const int f = m0s + mb * 16 + lr;
      const unsigned b = (unsigned)f / (unsigned)L;
      const int l = f - (int)b * L;
      float* orow = out + (size_t)b * 10368 + (size_t)(start * 8 + d) * 128
                    + (size_t)l * 1024 + lg * 4;
#pragma unroll
      for (int nb = 0; nb < 8; ++nb)
        *(f32x4*)(orow + nb * 16) = acc[nb][mb];
    }
  }
}

extern "C" void kernel_launch(void* const* d_in, const int* in_sizes, int n_in,
                              void* d_out, int out_size, void* d_ws, size_t ws_size,
                              hipStream_t stream) {
  const float* W = (const float*)d_in[0];
  const float* bias = (const float*)d_in[1];
  XPtrs xp;
  for (int i = 0; i < 17; ++i) xp.p[i] = (const float*)d_in[2 + i];
  float* out = (float*)d_out;
  unsigned short* ws = (unsigned short*)d_ws;   // 17*2048*16 B = 544 KiB

  Bases bb;
  int base = 0;
  for (int i = 0; i < 17; ++i) {
    bb.v[i] = base;
    int L = 9 - ((i < 8) ? (8 - i) : (i - 8));
    base += 32 * L;              // 256-row chunks per diag
  }
  bb.v[17] = base;               // 2592 blocks

  convert_w_kernel<<<34, 1024, 0, stream>>>(W, ws);
  diag_linear_kernel<<<base, 256, 0, stream>>>(xp, bb, ws, bias, out);
}

// Round 6
// 155.561 us; speedup vs baseline: 2.9512x; 1.0691x over previous
//
#include <hip/hip_runtime.h>
#include <hip/hip_bf16.h>

typedef __attribute__((ext_vector_type(8))) short short8;
typedef __attribute__((ext_vector_type(4))) float f32x4;
typedef __attribute__((ext_vector_type(4))) unsigned int u32x4;

struct XPtrs { const float* p[17]; };
struct Bases { int v[18]; };

#define CPB 5  // units (of 64 rows) per block

__device__ __forceinline__ unsigned short f2bf(float f) {
  unsigned u = __float_as_uint(f);
  return (unsigned short)((u + 0x7fffu + ((u >> 16) & 1u)) >> 16);  // RNE
}

// ---------------- pre-kernel: W fp32 -> bf16, fragment-packed into ws ----
// Per diag d: 2048 slots of 16 B. slot = sg*128 + n  (sg = s*4 + g)
// slot holds W[d][n][k] for k = sg*8 .. sg*8+7 as 8 bf16 (RNE).
__global__ __launch_bounds__(1024) void convert_w_kernel(
    const float* __restrict__ W, unsigned short* __restrict__ ws) {
  const int tid = blockIdx.x * 1024 + threadIdx.x;  // 0 .. 17*2048-1
  const int d  = tid >> 11;
  const int s2 = tid & 2047;
  const int sg = s2 >> 7;     // 0..15
  const int n  = s2 & 127;
  const float* src = W + ((size_t)d * 128 + n) * 128 + sg * 8;
  float4 a = *(const float4*)(src);
  float4 b = *(const float4*)(src + 4);
  unsigned u0 = (unsigned)f2bf(a.x) | ((unsigned)f2bf(a.y) << 16);
  unsigned u1 = (unsigned)f2bf(a.z) | ((unsigned)f2bf(a.w) << 16);
  unsigned u2 = (unsigned)f2bf(b.x) | ((unsigned)f2bf(b.y) << 16);
  unsigned u3 = (unsigned)f2bf(b.z) | ((unsigned)f2bf(b.w) << 16);
  *(uint4*)(ws + (size_t)tid * 8) = make_uint4(u0, u1, u2, u3);
}

// pack two fp32 (lo, hi) -> one u32 of two bf16, round-half-up + v_perm
__device__ __forceinline__ unsigned pack_bf2(float lo, float hi) {
  unsigned rl = __float_as_uint(lo) + 0x8000u;
  unsigned rh = __float_as_uint(hi) + 0x8000u;
  // dst = { rh[31:16], rl[31:16] }  (bytes: idx0..3 = src1, idx4..7 = src0)
  return __builtin_amdgcn_perm(rh, rl, 0x07060302u);
}

// ---------------- main kernel ----------------
// 256 threads = 4 waves. Block owns up to CPB units of 64 rows in ONE
// diagonal. W+bias staged to LDS once; steady-state loop is barrier-free:
// convert unit i -> issue unit i+1 loads -> MFMA -> store. Load latency of
// unit i+1 hides under MFMA+stores of unit i (counted vmcnt, no drain).
__global__ __launch_bounds__(256) void diag_linear_kernel(
    XPtrs xp, Bases bb, const unsigned short* __restrict__ wsrc,
    const float* __restrict__ bias, float* __restrict__ out) {
  const int bid = blockIdx.x;
  int d = 0;
#pragma unroll
  for (int i = 1; i < 17; ++i) d += (bid >= bb.v[i]) ? 1 : 0;
  const int L = 9 - ((d < 8) ? (8 - d) : (d - 8));
  const int start = (d > 8) ? (d - 8) : 0;
  const float* __restrict__ x = xp.p[d];
  const int nunits = 128 * L;                // 64-row units in this diag
  const int u0 = (bid - bb.v[d]) * CPB;
  const int nit = min(CPB, nunits - u0);

  const int t = threadIdx.x;
  const int lane = t & 63;
  const int wave = t >> 6;       // 0..3
  const int lr = lane & 15;
  const int lg = lane >> 4;

  __shared__ unsigned short wlds[2048 * 8];  // 32 KiB
  __shared__ float blds[128];                // bias

  // ---- stage W[d] (pre-packed bf16) + bias via async global->LDS ----
  {
    const unsigned short* gw = wsrc + (size_t)d * 16384;
    typedef const __attribute__((address_space(1))) unsigned int* gas_u32;
    typedef __attribute__((address_space(3))) unsigned int* las_u32;
#pragma unroll
    for (int r = 0; r < 8; ++r) {
      const int slotbase = (wave * 8 + r) * 64;
      __builtin_amdgcn_global_load_lds(
          (gas_u32)(const void*)(gw + (size_t)(slotbase + lane) * 8),
          (las_u32)(void*)(wlds + (size_t)slotbase * 8),
          16, 0, 0);
    }
    if (t < 32) {  // lanes 0..31 -> blds[0..127], 16B/lane
      __builtin_amdgcn_global_load_lds(
          (gas_u32)(const void*)(bias + d * 128 + t * 4),
          (las_u32)(void*)(blds), 16, 0, 0);
    }
  }

  // ---- prefetch unit u0 into registers (overlaps W staging) ----
  float4 pf[8];
  {
    const float* xr = x + ((size_t)(u0 * 64 + wave * 16 + lr)) * 128 + lg * 8;
#pragma unroll
    for (int s = 0; s < 4; ++s) {
      pf[2 * s]     = *(const float4*)(xr + s * 32);
      pf[2 * s + 1] = *(const float4*)(xr + s * 32 + 4);
    }
  }

  __syncthreads();   // W + bias resident

  for (int it = 0; it < nit; ++it) {
    const int u = u0 + it;

    // convert current prefetch -> bf16 fragments (half-up + v_perm pack)
    short8 xf[4];
#pragma unroll
    for (int s = 0; s < 4; ++s) {
      float4 a0 = pf[2 * s], a1 = pf[2 * s + 1];
      u32x4 w;
      w.x = pack_bf2(a0.x, a0.y);
      w.y = pack_bf2(a0.z, a0.w);
      w.z = pack_bf2(a1.x, a1.y);
      w.w = pack_bf2(a1.z, a1.w);
      xf[s] = __builtin_bit_cast(short8, w);
    }

    // issue next unit's loads early (clamped on last iter; wave-uniform)
    {
      const int un = (it + 1 < nit) ? (u + 1) : u;
      const float* xr =
          x + ((size_t)(un * 64 + wave * 16 + lr)) * 128 + lg * 8;
#pragma unroll
      for (int s = 0; s < 4; ++s) {
        pf[2 * s]     = *(const float4*)(xr + s * 32);
        pf[2 * s + 1] = *(const float4*)(xr + s * 32 + 4);
      }
    }

    // acc init = bias (from LDS; lane quad = couts nb*16+lg*4+0..3)
    f32x4 acc[8];
#pragma unroll
    for (int nb = 0; nb < 8; ++nb)
      acc[nb] = *(const f32x4*)&blds[nb * 16 + lg * 4];

    // MFMA: A = W frag (couts), B = X frag (16 batch rows)
#pragma unroll
    for (int s = 0; s < 4; ++s) {
#pragma unroll
      for (int nb = 0; nb < 8; ++nb) {
        short8 wf = *(const short8*)
            &wlds[(size_t)((s * 4 + lg) * 128 + nb * 16 + lr) * 8];
        acc[nb] = __builtin_amdgcn_mfma_f32_16x16x32_bf16(wf, xf[s], acc[nb], 0, 0, 0);
      }
    }

    // epilogue: D[cout = nb*16+lg*4+v][brow = lr] -> 512B contiguous per row
    const int f = u * 64 + wave * 16 + lr;
    const unsigned b = (unsigned)f / (unsigned)L;
    const int l = f - (int)b * L;
    float* orow = out + (size_t)b * 10368 + (size_t)(start * 8 + d) * 128
                  + (size_t)l * 1024 + lg * 4;
#pragma unroll
    for (int nb = 0; nb < 8; ++nb)
      *(f32x4*)(orow + nb * 16) = acc[nb];
  }
}

extern "C" void kernel_launch(void* const* d_in, const int* in_sizes, int n_in,
                              void* d_out, int out_size, void* d_ws, size_t ws_size,
                              hipStream_t stream) {
  const float* W = (const float*)d_in[0];
  const float* bias = (const float*)d_in[1];
  XPtrs xp;
  for (int i = 0; i < 17; ++i) xp.p[i] = (const float*)d_in[2 + i];
  float* out = (float*)d_out;
  unsigned short* ws = (unsigned short*)d_ws;   // 17*2048*16 B = 544 KiB

  Bases bb;
  int base = 0;
  for (int i = 0; i < 17; ++i) {
    bb.v[i] = base;
    int L = 9 - ((i < 8) ? (8 - i) : (i - 8));
    base += (128 * L + CPB - 1) / CPB;
  }
  bb.v[17] = base;   // ~2080 blocks

  convert_w_kernel<<<34, 1024, 0, stream>>>(W, ws);
  diag_linear_kernel<<<base, 256, 0, stream>>>(xp, bb, ws, bias, out);
}